// Round 1
// baseline (274.978 us; speedup 1.0000x reference)
//
#include <hip/hip_runtime.h>

// x [B=8, H=224, W=224, D=8, C=8] fp32, out [8, 8, 8, 10] fp32.
// DC = 64 contiguous channels == one wave: lane = channel.
// Each wave owns GW=8 output columns, loads SPAN=17 (8 + 9 halo) columns/row,
// streams a 14-row output strip (23 input rows). The 2x2 max-pyramid
// (P_s = 2x2 max of P_{s-1}) is held entirely in registers: no LDS, no
// cross-lane ops in the hot loop (the old version chained 36 ds_bpermute/row).
#define BB 8
#define HH 224
#define WW 224
#define DCH 64
#define NS 10
#define GW 8                    // owned output columns per wave
#define SPAN (GW + NS - 1)      // 17 columns spanned per wave
#define STRIPR 14               // output rows per strip
#define NSTRIPR 16              // 16 * 14 = 224
#define NCB 7                   // column-blocks of 32 cols (4 waves * 8)
#define NBLK (BB * NSTRIPR * NCB) // 896 blocks = 8 XCDs * 112

__global__ void zero_kernel(float* out, int n) {
    int i = blockIdx.x * blockDim.x + threadIdx.x;
    if (i < n) out[i] = 0.0f;
}

__global__ void finalize_kernel(float* out, int n) {
    int i = blockIdx.x * blockDim.x + threadIdx.x;
    if (i < n) out[i] = fmaxf(out[i], 0.0f) + 1.0f;
}

template<bool INTERIOR>
__device__ __forceinline__ float maskedSum(const float* p, int w0, int s) {
    if (INTERIOR) {
        // all 8 owned columns valid at every scale (w0 <= 200 -> w0+7+9 <= 223)
        return ((p[0] + p[1]) + (p[2] + p[3])) + ((p[4] + p[5]) + (p[6] + p[7]));
    } else {
        float t = 0.0f;
#pragma unroll
        for (int k = 0; k < GW; ++k) t += (w0 + k <= WW - s) ? p[k] : 0.0f;
        return t;
    }
}

template<bool INTERIOR>
__device__ __forceinline__ void pool_body(const float* __restrict__ x,
                                          float* __restrict__ out,
                                          int b, int w0, int row0, int lane) {
    const int rend = min(row0 + STRIPR + NS - 1, HH);

    float acc[NS];
#pragma unroll
    for (int s = 0; s < NS; ++s) acc[s] = 0.0f;

    // Ragged prev-row pyramid state: pv[lv] holds previous row of level lv+1
    // (lv=0: raw x row, width 17; lv=8: P_9 row, width 9). 117 registers.
    float pv[NS - 1][SPAN];
#pragma unroll
    for (int lv = 0; lv < NS - 1; ++lv)
#pragma unroll
        for (int w = 0; w < SPAN - lv; ++w) pv[lv][w] = 0.0f;

    // Column byte offsets, biased by 8 columns so imm offsets fit +/-2048*? :
    // interior -> compile-time constants folded into load offsets.
    int koff[SPAN];
#pragma unroll
    for (int k = 0; k < SPAN; ++k) {
        int c = INTERIOR ? (w0 + k) : min(w0 + k, WW - 1); // clamp right edge
        koff[k] = (c - w0 - 8) * DCH;
    }

    const float* px = x + (((size_t)(b * HH + row0) * WW + w0 + 8) * DCH + lane);
    const ptrdiff_t rstride = (ptrdiff_t)WW * DCH;

    float cp[SPAN]; // current x row (then prefetch buffer for next row)
#pragma unroll
    for (int k = 0; k < SPAN; ++k) cp[k] = px[koff[k]];
    px += rstride;

    for (int h = row0; h < rend; ++h) {
        // scale 1: sum the raw row over owned columns
        if (h < row0 + STRIPR) acc[0] += maskedSum<INTERIOR>(cp, w0, 1);

        // level 2: vertical max vs previous x row, then horizontal pair max
        float vm[SPAN];
#pragma unroll
        for (int w = 0; w < SPAN; ++w) vm[w] = fmaxf(pv[0][w], cp[w]);
#pragma unroll
        for (int w = 0; w < SPAN; ++w) pv[0][w] = cp[w];

        // cp is dead now: prefetch next row under the remaining ~300 VALU ops
        if (h + 1 < rend) {
#pragma unroll
            for (int k = 0; k < SPAN; ++k) cp[k] = px[koff[k]];
            px += rstride;
        }

        float c[SPAN - 1];
#pragma unroll
        for (int w = 0; w < SPAN - 1; ++w) c[w] = fmaxf(vm[w], vm[w + 1]);
        if (h - 1 >= row0 && h - 1 < row0 + STRIPR)
            acc[1] += maskedSum<INTERIOR>(c, w0, 2);

        // levels 3..10: c enters with width SPAN-lv, exits width SPAN-lv-1
#pragma unroll
        for (int lv = 1; lv < NS - 1; ++lv) {
            const int wid = SPAN - lv;
            float vm2[SPAN];
#pragma unroll
            for (int w = 0; w < wid; ++w) vm2[w] = fmaxf(pv[lv][w], c[w]);
#pragma unroll
            for (int w = 0; w < wid; ++w) pv[lv][w] = c[w];
#pragma unroll
            for (int w = 0; w < wid - 1; ++w) c[w] = fmaxf(vm2[w], vm2[w + 1]);
            const int r = h - lv - 1; // output row of P_{lv+2}
            if (r >= row0 && r < row0 + STRIPR)
                acc[lv + 1] += maskedSum<INTERIOR>(c, w0, lv + 2);
        }
    }

    // lane = channel: one atomic per scale, no cross-lane reduction needed
    float* ob = out + (size_t)(b * DCH + lane) * NS;
#pragma unroll
    for (int s = 0; s < NS; ++s) atomicAdd(&ob[s], acc[s]);
}

__global__ __launch_bounds__(256, 2) void pool_kernel(const float* __restrict__ x,
                                                      float* __restrict__ out) {
    // Bijective XCD swizzle (896 = 8*112): XCD k gets logical [k*112,(k+1)*112)
    // == all of batch k -> halo re-reads and output atomics stay in one L2.
    const int phys = blockIdx.x;
    const int logical = (phys & 7) * (NBLK / 8) + (phys >> 3);
    const int cb = logical % NCB;
    const int hs = (logical / NCB) % NSTRIPR;
    const int b  = logical / (NCB * NSTRIPR);

    const int wv   = threadIdx.x >> 6;
    const int lane = threadIdx.x & 63;
    const int w0   = cb * (4 * GW) + wv * GW; // adjacent waves -> adjacent cols (L1 halo hits)
    const int row0 = hs * STRIPR;

    if (w0 + SPAN <= WW) pool_body<true>(x, out, b, w0, row0, lane);
    else                 pool_body<false>(x, out, b, w0, row0, lane);
}

extern "C" void kernel_launch(void* const* d_in, const int* in_sizes, int n_in,
                              void* d_out, int out_size, void* d_ws, size_t ws_size,
                              hipStream_t stream) {
    const float* x = (const float*)d_in[0];
    float* out = (float*)d_out;
    const int nblk = (out_size + 255) / 256;
    zero_kernel<<<nblk, 256, 0, stream>>>(out, out_size);
    pool_kernel<<<NBLK, 256, 0, stream>>>(x, out);
    finalize_kernel<<<nblk, 256, 0, stream>>>(out, out_size);
}

// Round 2
// 251.843 us; speedup vs baseline: 1.0919x; 1.0919x over previous
//
#include <hip/hip_runtime.h>

// x [B=8, H=224, W=224, D=8, C=8] fp32, out [8, 8, 8, 10] fp32.
// lane = channel (DC=64 == wave width): pyramid is cross-lane-free.
// Round-1 lesson: GW=8 needed ~170 live floats -> allocator kept only 108 in
// arch VGPRs and shuttled the pyramid through AGPR/scratch (~230 extra ops/row).
// GW=4 state: pv 81 + 2x13 row buffers + acc 10 ~= 130 regs -> fits at 3 waves/EU.
#define BB 8
#define HH 224
#define WW 224
#define DCH 64
#define NS 10
#define GW 4                      // owned output columns per wave
#define SPAN (GW + NS - 1)        // 13 columns spanned
#define STRIPR 16                 // output rows per strip
#define NSTRIPR 14                // 14*16 = 224
#define NCB 14                    // 14 col-blocks * (4 waves * 4 cols) = 224
#define NBLK (BB * NSTRIPR * NCB) // 1568 = 8 XCDs * 196 (one full batch per XCD)

__global__ void zero_kernel(float* out, int n) {
    int i = blockIdx.x * blockDim.x + threadIdx.x;
    if (i < n) out[i] = 0.0f;
}

__global__ void finalize_kernel(float* out, int n) {
    int i = blockIdx.x * blockDim.x + threadIdx.x;
    if (i < n) out[i] = fmaxf(out[i], 0.0f) + 1.0f;
}

template<bool INTERIOR>
__device__ __forceinline__ float sum4(const float* c, int w0, int s) {
    if (INTERIOR) return (c[0] + c[1]) + (c[2] + c[3]); // w0+3 <= 214 <= 224-s for all s
    float t = 0.0f;
#pragma unroll
    for (int k = 0; k < GW; ++k) t += (w0 + k <= WW - s) ? c[k] : 0.0f;
    return t;
}

// One input row through the 2x2 max-pyramid cascade (in place on c), with
// prefetch of the next row into nb issued FIRST so vmem hides under ~200 VALU.
template<bool INTERIOR>
__device__ __forceinline__ void row_step(const float*& px, ptrdiff_t rstride,
                                         int h, int rend, int row0, int w0,
                                         const int (&koff)[SPAN],
                                         float (&c)[SPAN], float (&nb)[SPAN],
                                         float (&pv)[NS - 1][SPAN], float (&acc)[NS]) {
    if (h + 1 < rend) { // uniform branch
        px += rstride;
        if (INTERIOR) {
#pragma unroll
            for (int k = 0; k < SPAN; ++k) nb[k] = px[k * DCH]; // imm offsets <= 3072B
        } else {
#pragma unroll
            for (int k = 0; k < SPAN; ++k) nb[k] = px[koff[k]];
        }
    }
    if (h < row0 + STRIPR) acc[0] += sum4<INTERIOR>(c, w0, 1); // scale 1 = raw row
#pragma unroll
    for (int lv = 0; lv < NS - 1; ++lv) {
        const int wid = SPAN - lv; // width of level-(lv+1) row entering
#pragma unroll
        for (int w = 0; w < wid; ++w) { // vertical max + rotate prev
            float t = fmaxf(pv[lv][w], c[w]);
            pv[lv][w] = c[w];
            c[w] = t;
        }
#pragma unroll
        for (int w = 0; w + 1 < wid; ++w) c[w] = fmaxf(c[w], c[w + 1]); // horizontal
        const int r = h - lv - 1; // output row of scale lv+2
        if (r >= row0 && r < row0 + STRIPR)
            acc[lv + 1] += sum4<INTERIOR>(c, w0, lv + 2);
    }
}

template<bool INTERIOR>
__device__ __forceinline__ void pool_body(const float* __restrict__ x,
                                          int b, int w0, int row0, int lane,
                                          float (&acc)[NS]) {
    const int rend = min(row0 + STRIPR + NS - 1, HH);

    float pv[NS - 1][SPAN]; // ragged: level lv uses width SPAN-lv -> 81 regs live
#pragma unroll
    for (int lv = 0; lv < NS - 1; ++lv)
#pragma unroll
        for (int w = 0; w < SPAN - lv; ++w) pv[lv][w] = 0.0f;

    int koff[SPAN]; // boundary only (right-edge clamp); interior path DCEs it
#pragma unroll
    for (int k = 0; k < SPAN; ++k)
        koff[k] = (INTERIOR ? k : (min(w0 + k, WW - 1) - w0)) * DCH;

    const float* px = x + (((size_t)(b * HH + row0) * WW + w0) * DCH + lane);
    const ptrdiff_t rstride = (ptrdiff_t)WW * DCH;

    float cA[SPAN], cB[SPAN]; // ping-pong row buffers (no copy between rows)
#pragma unroll
    for (int k = 0; k < SPAN; ++k) cA[k] = INTERIOR ? px[k * DCH] : px[koff[k]];

    int h = row0;
    for (; h + 1 < rend; h += 2) {
        row_step<INTERIOR>(px, rstride, h,     rend, row0, w0, koff, cA, cB, pv, acc);
        row_step<INTERIOR>(px, rstride, h + 1, rend, row0, w0, koff, cB, cA, pv, acc);
    }
    if (h < rend)
        row_step<INTERIOR>(px, rstride, h, rend, row0, w0, koff, cA, cB, pv, acc);
}

__global__ __launch_bounds__(256, 3) void pool_kernel(const float* __restrict__ x,
                                                      float* __restrict__ out) {
    __shared__ float red[4 * DCH * NS]; // 10.25 KB: block reduction before atomics

    // Bijective XCD swizzle: 1568 = 8*196 -> XCD k owns exactly batch k
    // (halo re-reads and output atomics stay inside one L2).
    const int phys = blockIdx.x;
    const int logical = (phys & 7) * (NBLK / 8) + (phys >> 3);
    const int b  = logical / (NSTRIPR * NCB);
    const int r2 = logical - b * (NSTRIPR * NCB);
    const int hs = r2 / NCB;
    const int cb = r2 - hs * NCB;

    const int wv   = threadIdx.x >> 6;
    const int lane = threadIdx.x & 63;
    const int w0   = cb * (4 * GW) + wv * GW; // adjacent waves -> adjacent cols
    const int row0 = hs * STRIPR;

    float acc[NS];
#pragma unroll
    for (int s = 0; s < NS; ++s) acc[s] = 0.0f;

    // Wave-uniform branch; __syncthreads kept OUTSIDE (waves in the last
    // column-block diverge interior/boundary).
    if (w0 + SPAN <= WW) pool_body<true >(x, b, w0, row0, lane, acc);
    else                 pool_body<false>(x, b, w0, row0, lane, acc);

#pragma unroll
    for (int s = 0; s < NS; ++s) red[(wv * DCH + lane) * NS + s] = acc[s];
    __syncthreads();
    // 640 sums / 256 threads, then one atomic each: 4x fewer atomics
    // (WRITE_SIZE counts 32B per atomic: round-1's 70MB was pure atomic traffic).
    for (int i = threadIdx.x; i < DCH * NS; i += 256) {
        const int ch = i / NS;
        const int s  = i - ch * NS;
        float v = red[ch * NS + s] + red[(DCH + ch) * NS + s]
                + red[(2 * DCH + ch) * NS + s] + red[(3 * DCH + ch) * NS + s];
        atomicAdd(&out[((size_t)b * DCH + ch) * NS + s], v);
    }
}

extern "C" void kernel_launch(void* const* d_in, const int* in_sizes, int n_in,
                              void* d_out, int out_size, void* d_ws, size_t ws_size,
                              hipStream_t stream) {
    const float* x = (const float*)d_in[0];
    float* out = (float*)d_out;
    const int nblk = (out_size + 255) / 256;
    zero_kernel<<<nblk, 256, 0, stream>>>(out, out_size);
    pool_kernel<<<NBLK, 256, 0, stream>>>(x, out);
    finalize_kernel<<<nblk, 256, 0, stream>>>(out, out_size);
}

// Round 3
// 204.687 us; speedup vs baseline: 1.3434x; 1.2304x over previous
//
#include <hip/hip_runtime.h>

// x [B=8, H=224, W=224, D=8, C=8] fp32, out [8, 8, 8, 10] fp32.
// Layout (round-0 style): lane = w-column (55 owned + 9 halo per 64-lane wave),
// 2 channels per lane (float2). Horizontal neighbor (col+1) via DPP wave_shl:1
// (ctrl 0x130, full VALU rate) instead of __shfl_down's ds_bpermute -- round 0
// spent ~58us in the DS pipe on 36 serialized shuffles/row; this kernel has
// ZERO cross-lane DS ops in the hot loop.
// Round-1/2 lesson: big per-thread arrays (GW-column register pyramid) trigger
// the allocator's AGPR-shuttle (84 arch VGPR vs 117 live floats -> 2x VALU).
// Here state is ~52 floats -> comfortably resident.
#define BB 8
#define HH 224
#define WW 224
#define DCH 64
#define NS 10
#define SEG 55    // owned output columns per wave (lanes 55..63 = halo)
#define NSEG 5    // 5*55 = 275 >= 224 (last segment ragged)
#define STRIP 56  // output rows per h-strip
#define NHS 4     // 4*56 = 224
#define NCG 8     // 8 channel-groups of 8 ch per block (wave = 2 ch)
#define NBLK (BB * NCG * NSEG * NHS) // 1280 = 8 XCDs * 160 (one batch per XCD)

__global__ void zero_kernel(float* out, int n) {
    int i = blockIdx.x * blockDim.x + threadIdx.x;
    if (i < n) out[i] = 0.0f;
}

__global__ void finalize_kernel(float* out, int n) {
    int i = blockIdx.x * blockDim.x + threadIdx.x;
    if (i < n) out[i] = fmaxf(out[i], 0.0f) + 1.0f;
}

// lane i <- lane i+1, full-wave shift (DPP WAVE_SHL1 = 0x130). Lane 63 gets 0
// (bound_ctrl) -- only ever feeds halo/masked outputs.
__device__ __forceinline__ float dpp_shl1(float v) {
    return __int_as_float(__builtin_amdgcn_update_dpp(
        0, __float_as_int(v), 0x130, 0xF, 0xF, true));
}

// One input row through the 2x2 max cascade. PHASE: 0 = warmup (guard r>=row0),
// 1 = steady (no guards, 47 of 65 rows), 2 = tail (guard r<row0+STRIP).
template<int PHASE>
__device__ __forceinline__ void row_body(int h, int row0, const float (&m)[NS],
                                         float (&cp)[2], float (&prev)[NS - 1][2],
                                         float (&acc)[NS][2]) {
    if (PHASE != 2) { // scale 1: raw row (warmup/steady always have h in strip)
        acc[0][0] = fmaf(cp[0], m[0], acc[0][0]);
        acc[0][1] = fmaf(cp[1], m[0], acc[0][1]);
    }
#pragma unroll
    for (int lv = 0; lv < NS - 1; ++lv) { // level lv -> scale lv+2, out row h-lv-1
        float vm0 = fmaxf(prev[lv][0], cp[0]); // vertical max (rows h-1, h)
        float vm1 = fmaxf(prev[lv][1], cp[1]);
        prev[lv][0] = cp[0];                   // rotate history
        prev[lv][1] = cp[1];
        cp[0] = fmaxf(vm0, dpp_shl1(vm0));     // horizontal max (cols j, j+1)
        cp[1] = fmaxf(vm1, dpp_shl1(vm1));
        bool on = true; // uniform (h, row0 scalar) -> s_cmp + s_cbranch
        if (PHASE == 0) on = (h - lv - 1) >= row0;
        if (PHASE == 2) on = (h - lv - 1) < row0 + STRIP;
        if (on) {
            acc[lv + 1][0] = fmaf(cp[0], m[lv + 1], acc[lv + 1][0]);
            acc[lv + 1][1] = fmaf(cp[1], m[lv + 1], acc[lv + 1][1]);
        }
    }
}

__global__ __launch_bounds__(256, 4) void pool_kernel(const float* __restrict__ x,
                                                      float* __restrict__ out) {
    // Bijective XCD swizzle: 1280 = 8*160 -> XCD k owns batch k (halo re-reads
    // and atomics stay in one L2). Within a batch, the 8 channel-group blocks
    // of one (hs,ws) tile are adjacent -> they re-read the same x lines (L2 hit).
    const int phys = blockIdx.x;
    const int logical = (phys & 7) * (NBLK / 8) + (phys >> 3);
    const int b = logical / (NCG * NSEG * NHS);
    const int r = logical % (NCG * NSEG * NHS);
    const int cg = r & 7;
    const int ws = (r >> 3) % NSEG;
    const int hs = (r >> 3) / NSEG;

    const int wv   = threadIdx.x >> 6;
    const int lane = threadIdx.x & 63;
    const int ch   = cg * 8 + wv * 2;      // 2 channels per lane, 8 per block
    const int col  = ws * SEG + lane;
    const int row0 = hs * STRIP;
    const int rend = min(row0 + STRIP + NS - 1, HH);

    float m[NS]; // per-scale column ownership (0/1, used via fma)
#pragma unroll
    for (int s = 1; s <= NS; ++s)
        m[s - 1] = (lane < SEG && col <= WW - s) ? 1.0f : 0.0f;

    float prev[NS - 1][2], acc[NS][2], cp[2], nv[2];
#pragma unroll
    for (int lv = 0; lv < NS - 1; ++lv) { prev[lv][0] = 0.0f; prev[lv][1] = 0.0f; }
#pragma unroll
    for (int s = 0; s < NS; ++s) { acc[s][0] = 0.0f; acc[s][1] = 0.0f; }
    nv[0] = 0.0f; nv[1] = 0.0f;

    const bool colok = (col < WW);
    const float* px = x + (((size_t)(b * HH + row0) * WW + col) * DCH + ch);
    const ptrdiff_t rstride = (ptrdiff_t)WW * DCH;

    if (colok) { float2 t = *(const float2*)px; nv[0] = t.x; nv[1] = t.y; }

#define ROW_STEP(P)                                                          \
    {                                                                        \
        cp[0] = nv[0]; cp[1] = nv[1];                                        \
        if (h + 1 < rend) { /* uniform: prefetch next row under the VALU */  \
            px += rstride;                                                   \
            if (colok) { float2 t = *(const float2*)px; nv[0] = t.x; nv[1] = t.y; } \
        }                                                                    \
        row_body<P>(h, row0, m, cp, prev, acc);                              \
    }

    int h = row0;
    const int warm_end = row0 + NS - 1;                // 9 warmup rows
    for (; h < warm_end; ++h) ROW_STEP(0)
    const int steady_end = min(row0 + STRIP, rend);    // 47 branch-free rows
    for (; h < steady_end; ++h) ROW_STEP(1)
    for (; h < rend; ++h) ROW_STEP(2)                  // <=9 tail rows
#undef ROW_STEP

    // Wave butterfly reduction (one-time), then lane 0 atomics 20 partials.
#pragma unroll
    for (int s = 0; s < NS; ++s) {
#pragma unroll
        for (int c = 0; c < 2; ++c) {
            float v = acc[s][c];
#pragma unroll
            for (int off = 32; off > 0; off >>= 1) v += __shfl_xor(v, off);
            if (lane == 0) atomicAdd(&out[((size_t)b * DCH + ch + c) * NS + s], v);
        }
    }
}

extern "C" void kernel_launch(void* const* d_in, const int* in_sizes, int n_in,
                              void* d_out, int out_size, void* d_ws, size_t ws_size,
                              hipStream_t stream) {
    const float* x = (const float*)d_in[0];
    float* out = (float*)d_out;
    const int nblk = (out_size + 255) / 256;
    zero_kernel<<<nblk, 256, 0, stream>>>(out, out_size);
    pool_kernel<<<NBLK, 256, 0, stream>>>(x, out);
    finalize_kernel<<<nblk, 256, 0, stream>>>(out, out_size);
}